// Round 8
// baseline (84.479 us; speedup 1.0000x reference)
//
#include <hip/hip_runtime.h>
#include <hip/hip_bf16.h>

// RetinaNet focal classification loss, MI355X. Output: scalar f32.
//
// Round-8: gt table moved from LDS to SGPRs. The r7 j-loop stalled on
// per-iteration ds_read->lgkmcnt->VALU (real VALU issue occupancy ~39%).
// gt values are wave-uniform, so the prep kernel writes a packed global
// table (8 floats/entry) and the main kernel reads it via a const
// __restrict__ pointer indexed only by (blockIdx.y, j) -> uniform address
// -> hipcc scalarizes to batched s_load, hoisted ahead of the VALU stream.
// Inner loop = pure VALU (1 SGPR operand max per instr, satisfied).
// probs loads prefetched before the j-loop. No LDS except reduction scratch.
//
// Fast path (per-image flag, stored in entry0 pad): all labels zero ->
// division-free predicates iou>=0.5 <=> fma(inter,3,-ga) >= area_a+eps ;
// iou<0.4 <=> fma(inter,3.5,-ga) < area_a+eps -> 13 VALU ops/pair,
// independent fmax chains. Slow path: exact cross-multiplication argmax.
//
// ws floats: [0..15] loss sums, [16..31] pos counts,
//            [32..543] gt table: 16 images x 32 entries x 8 floats
//            {x1,y1,x2,y2,-ga,ga,lab, (j==0: fastflag else 0)}

#define A_N 200000
#define B_N 16
#define G_N 32
#define APT 8
#define BLK 256
#define TILE (BLK * APT)                 // 2048
#define NBX ((A_N + TILE - 1) / TILE)    // 98

#define C_POS (0.25f * 0.69314718f)      // alpha * ln2   (log2 -> ln fold)
#define C_NEG (0.75f * 0.69314718f)      // (1-alpha) * ln2

// ---------------- prep: zero accumulators + build packed gt table ----------------
__global__ void rnl_prep(const float* __restrict__ y_true, float* __restrict__ ws) {
    const int t = threadIdx.x;
    if (t < 2 * B_N) ws[t] = 0.0f;
    if (t < B_N * G_N) {
        float cx = y_true[t * 5 + 0];
        float cy = y_true[t * 5 + 1];
        float w  = y_true[t * 5 + 2];
        float h  = y_true[t * 5 + 3];
        float lb = y_true[t * 5 + 4];
        float x1 = cx - 0.5f * w, y1 = cy - 0.5f * h;
        float x2 = cx + 0.5f * w, y2 = cy + 0.5f * h;
        float ga = (x2 - x1) * (y2 - y1);
        float* e = ws + 2 * B_N + t * 8;
        e[0] = x1; e[1] = y1; e[2] = x2; e[3] = y2;
        e[4] = -ga; e[5] = ga; e[6] = lb; e[7] = 0.0f;
    }
    __syncthreads();
    if (t < B_N) {                        // per-image fast flag -> entry0 pad
        bool allz = true;
        for (int j = 0; j < G_N; ++j)
            allz = allz && (y_true[(t * G_N + j) * 5 + 4] == 0.0f);
        ws[2 * B_N + t * (G_N * 8) + 7] = allz ? 1.0f : 0.0f;
    }
}

// ---------------- main ----------------
__launch_bounds__(BLK)
__global__ void rnl_main(const float4* __restrict__ anchors,
                         const float* __restrict__ probs,
                         const float* __restrict__ gtab,   // ws + 32
                         float* __restrict__ ws) {
    const int b = blockIdx.y;
    const int t = threadIdx.x;
    const int base = blockIdx.x * TILE + t;

    // uniform-address gt view for this image -> s_load candidates
    const float* __restrict__ g = gtab + b * (G_N * 8);
    const bool fast = (g[7] != 0.0f);       // block-uniform branch
    const float lab0 = g[6];

    // anchors + probs resident in regs for the whole j-loop
    float ax[APT], ay[APT], az[APT], aw[APT], pv[APT];
    #pragma unroll
    for (int k = 0; k < APT; ++k) {
        int idx  = base + k * BLK;
        int idxc = idx < A_N ? idx : A_N - 1;
        float4 an = anchors[idxc];
        ax[k] = an.x; ay[k] = an.y; az[k] = an.z; aw[k] = an.w;
        pv[k] = probs[b * A_N + idxc];      // prefetched under j-loop compute
    }

    float loss = 0.0f, cnt = 0.0f;

    if (fast) {
        // ---- fast path: all labels zero -> 13 ops/pair, fmax-chain trackers
        float m1[APT], m2[APT];
        #pragma unroll
        for (int k = 0; k < APT; ++k) { m1[k] = -1e30f; m2[k] = -1e30f; }

        #pragma unroll
        for (int j = 0; j < G_N; ++j) {
            const float gx1 = g[j * 8 + 0];
            const float gy1 = g[j * 8 + 1];
            const float gx2 = g[j * 8 + 2];
            const float gy2 = g[j * 8 + 3];
            const float nga = g[j * 8 + 4];
            #pragma unroll
            for (int k = 0; k < APT; ++k) {
                float ltx = fmaxf(ax[k], gx1);
                float lty = fmaxf(ay[k], gy1);
                float rbx = fminf(az[k], gx2);
                float rby = fminf(aw[k], gy2);
                float iw  = fmaxf(rbx - ltx, 0.0f);
                float ih  = fmaxf(rby - lty, 0.0f);
                float inter = iw * ih;
                m1[k] = fmaxf(m1[k], fmaf(inter, 3.0f, nga));
                m2[k] = fmaxf(m2[k], fmaf(inter, 3.5f, nga));
            }
        }
        #pragma unroll
        for (int k = 0; k < APT; ++k) {
            bool valid = (base + k * BLK) < A_N;
            float sa = (az[k] - ax[k]) * (aw[k] - ay[k]) + 1e-8f;
            bool pos = m1[k] >= sa;             // max iou >= 0.5
            bool neg = m2[k] <  sa;             // max iou <  0.4
            float p = __builtin_amdgcn_fmed3f(pv[k], 1e-7f, 1.0f - 1e-7f);
            float q = 1.0f - p;
            float x = pos ? p : q;              // label==0 -> pos implies target hit
            float w = pos ? C_POS * q * q : C_NEG * p * p;
            float l = w * (-__log2f(x));
            l = ((pos | neg) && valid) ? l : 0.0f;
            loss += l;
            cnt  += (pos && valid) ? 1.0f : 0.0f;
        }
    } else {
        // ---- slow path: exact argmax + label (general correctness)
        float bi[APT], bS[APT], bl[APT];
        #pragma unroll
        for (int k = 0; k < APT; ++k) { bi[k] = 0.0f; bS[k] = 1.0f; bl[k] = lab0; }

        #pragma unroll
        for (int j = 0; j < G_N; ++j) {
            const float gx1 = g[j * 8 + 0];
            const float gy1 = g[j * 8 + 1];
            const float gx2 = g[j * 8 + 2];
            const float gy2 = g[j * 8 + 3];
            const float ga  = g[j * 8 + 5];
            const float lb  = g[j * 8 + 6];
            #pragma unroll
            for (int k = 0; k < APT; ++k) {
                float ltx = fmaxf(ax[k], gx1);
                float lty = fmaxf(ay[k], gy1);
                float rbx = fminf(az[k], gx2);
                float rby = fminf(aw[k], gy2);
                float iw  = fmaxf(rbx - ltx, 0.0f);
                float ih  = fmaxf(rby - lty, 0.0f);
                float inter = iw * ih;
                float sa = (az[k] - ax[k]) * (aw[k] - ay[k]) + 1e-8f;
                float S  = sa + ga;
                // iou_j > iou_best <=> inter_j*S_best > inter_best*S_j
                bool better = inter * bS[k] > bi[k] * S;
                bi[k] = better ? inter : bi[k];
                bS[k] = better ? S     : bS[k];
                bl[k] = better ? lb    : bl[k];
            }
        }
        #pragma unroll
        for (int k = 0; k < APT; ++k) {
            bool valid = (base + k * BLK) < A_N;
            bool pos = 3.0f * bi[k] >= bS[k];   // max iou >= 0.5
            bool neg = 3.5f * bi[k] <  bS[k];   // max iou <  0.4
            bool tp  = pos && (bl[k] == 0.0f);  // one_hot(assigned, C=1) hit
            float p = __builtin_amdgcn_fmed3f(pv[k], 1e-7f, 1.0f - 1e-7f);
            float q = 1.0f - p;
            float x = tp ? p : q;
            float w = tp ? C_POS * q * q : C_NEG * p * p;
            float l = w * (-__log2f(x));
            l = ((pos | neg) && valid) ? l : 0.0f;
            loss += l;
            cnt  += (pos && valid) ? 1.0f : 0.0f;
        }
    }

    // block reduction: wave shuffle, then cross-wave via LDS, 2 atomics/block
    #pragma unroll
    for (int off = 32; off > 0; off >>= 1) {
        loss += __shfl_down(loss, off);
        cnt  += __shfl_down(cnt, off);
    }
    __shared__ float s_l[4], s_c[4];
    int wid  = t >> 6;
    int lane = t & 63;
    if (lane == 0) { s_l[wid] = loss; s_c[wid] = cnt; }
    __syncthreads();
    if (t == 0) {
        atomicAdd(&ws[b],       s_l[0] + s_l[1] + s_l[2] + s_l[3]);
        atomicAdd(&ws[B_N + b], s_c[0] + s_c[1] + s_c[2] + s_c[3]);
    }
}

__global__ void rnl_final(const float* __restrict__ ws, float* __restrict__ out) {
    if (threadIdx.x == 0) {
        float s = 0.0f;
        #pragma unroll
        for (int b = 0; b < B_N; ++b) {
            s += ws[b] / fmaxf(ws[B_N + b], 1.0f);
        }
        out[0] = s * (1.0f / (float)B_N);
    }
}

extern "C" void kernel_launch(void* const* d_in, const int* in_sizes, int n_in,
                              void* d_out, int out_size, void* d_ws, size_t ws_size,
                              hipStream_t stream) {
    const float* y_true     = (const float*)d_in[0];
    const float* y_classifs = (const float*)d_in[1];
    // d_in[2] = y_regressions: unused by the loss
    const float* anchors    = (const float*)d_in[3];
    float* ws = (float*)d_ws;

    rnl_prep<<<1, 512, 0, stream>>>(y_true, ws);

    dim3 grid(NBX, B_N);
    rnl_main<<<grid, BLK, 0, stream>>>((const float4*)anchors, y_classifs,
                                       ws + 2 * B_N, ws);

    rnl_final<<<1, 64, 0, stream>>>(ws, (float*)d_out);
}

// Round 9
// 48.006 us; speedup vs baseline: 1.7597x; 1.7597x over previous
//
#include <hip/hip_runtime.h>
#include <hip/hip_bf16.h>

// RetinaNet focal classification loss, MI355X. Output: scalar f32.
//
// Round-9 = round-7 (best: 40us, VGPR 64) with the j-loop PARTIALLY unrolled.
// r7's full unroll made a ~26KB straight-line fast path (I$ is 32KB) executed
// once per thread -> instruction-fetch streaming + per-j ds_read->lgkmcnt
// serialization. r8's SGPR-table attempt gave VGPR 204 / occupancy 9.7% ->
// 84us (hoisting, not streaming). Here: #pragma unroll 4 -> ~3.5KB body
// looping 8x (I$ warm), 8 ds_read_b128 batched per iteration, one lgkmcnt
// per 416 VALU ops. gt packed as two float4s (sbox + smeta{-ga,ga,lab,0}).
//
// Fast path (all labels zero, __ballot-detected): division-free predicates
// iou>=0.5 <=> fma(inter,3,-ga) >= area_a+eps ; iou<0.4 <=> fma(inter,3.5,-ga)
// < area_a+eps -> 13 VALU ops/pair, independent fmax chains.
// Slow path: exact cross-multiplication argmax.
//
// ws: 32 floats: [0..15] per-image loss sums, [16..31] per-image pos counts.

#define A_N 200000
#define B_N 16
#define G_N 32
#define APT 8
#define BLK 256
#define TILE (BLK * APT)                 // 2048
#define NBX ((A_N + TILE - 1) / TILE)    // 98

#define C_POS (0.25f * 0.69314718f)      // alpha * ln2   (log2 -> ln fold)
#define C_NEG (0.75f * 0.69314718f)      // (1-alpha) * ln2

__launch_bounds__(BLK)
__global__ void rnl_main(const float4* __restrict__ anchors,
                         const float* __restrict__ probs,
                         const float* __restrict__ y_true,
                         float* __restrict__ ws) {
    __shared__ float4 sbox[G_N];        // gt corners {x1,y1,x2,y2}
    __shared__ float4 smeta[G_N];       // {-ga, ga, lab, 0}
    __shared__ float  sraw[G_N * 5];
    __shared__ int    sflag;

    const int b = blockIdx.y;
    const int t = threadIdx.x;

    if (t < G_N * 5) sraw[t] = y_true[b * (G_N * 5) + t];
    __syncthreads();
    if (t < 64) {                          // wave 0 builds gt table + flag
        float lb = 0.0f;
        if (t < G_N) {
            float cx = sraw[t * 5 + 0], cy = sraw[t * 5 + 1];
            float w  = sraw[t * 5 + 2], h  = sraw[t * 5 + 3];
            lb = sraw[t * 5 + 4];
            float x1 = cx - 0.5f * w, y1 = cy - 0.5f * h;
            float x2 = cx + 0.5f * w, y2 = cy + 0.5f * h;
            float ga = (x2 - x1) * (y2 - y1);
            sbox[t]  = make_float4(x1, y1, x2, y2);
            smeta[t] = make_float4(-ga, ga, lb, 0.0f);
        }
        unsigned long long bal = __ballot(lb != 0.0f);
        if (t == 0) sflag = (bal == 0ULL) ? 1 : 0;
    }
    __syncthreads();

    const int base = blockIdx.x * TILE + t;
    const float lab0 = smeta[0].z;

    float loss = 0.0f, cnt = 0.0f;

    // anchors + probs resident in regs for the whole j-loop
    float ax[APT], ay[APT], az[APT], aw[APT], pv[APT];
    #pragma unroll
    for (int k = 0; k < APT; ++k) {
        int idx  = base + k * BLK;
        int idxc = idx < A_N ? idx : A_N - 1;
        float4 an = anchors[idxc];
        ax[k] = an.x; ay[k] = an.y; az[k] = an.z; aw[k] = an.w;
        pv[k] = probs[b * A_N + idxc];
    }

    if (sflag) {
        // ---- fast path: all labels zero -> 13 ops/pair, fmax-chain trackers
        float m1[APT], m2[APT];
        #pragma unroll
        for (int k = 0; k < APT; ++k) { m1[k] = -1e30f; m2[k] = -1e30f; }

        #pragma unroll 4
        for (int j = 0; j < G_N; ++j) {
            float4 gb  = sbox[j];
            float  nga = smeta[j].x;
            #pragma unroll
            for (int k = 0; k < APT; ++k) {
                float ltx = fmaxf(ax[k], gb.x);
                float lty = fmaxf(ay[k], gb.y);
                float rbx = fminf(az[k], gb.z);
                float rby = fminf(aw[k], gb.w);
                float iw  = fmaxf(rbx - ltx, 0.0f);
                float ih  = fmaxf(rby - lty, 0.0f);
                float inter = iw * ih;
                m1[k] = fmaxf(m1[k], fmaf(inter, 3.0f, nga));
                m2[k] = fmaxf(m2[k], fmaf(inter, 3.5f, nga));
            }
        }
        #pragma unroll
        for (int k = 0; k < APT; ++k) {
            bool valid = (base + k * BLK) < A_N;
            float sa = (az[k] - ax[k]) * (aw[k] - ay[k]) + 1e-8f;
            bool pos = m1[k] >= sa;             // max iou >= 0.5
            bool neg = m2[k] <  sa;             // max iou <  0.4
            float p = __builtin_amdgcn_fmed3f(pv[k], 1e-7f, 1.0f - 1e-7f);
            float q = 1.0f - p;
            float x = pos ? p : q;              // label==0 -> pos implies target hit
            float w = pos ? C_POS * q * q : C_NEG * p * p;
            float l = w * (-__log2f(x));
            l = ((pos | neg) && valid) ? l : 0.0f;
            loss += l;
            cnt  += (pos && valid) ? 1.0f : 0.0f;
        }
    } else {
        // ---- slow path: exact argmax + label (general correctness)
        float bi[APT], bS[APT], bl[APT];
        #pragma unroll
        for (int k = 0; k < APT; ++k) { bi[k] = 0.0f; bS[k] = 1.0f; bl[k] = lab0; }

        #pragma unroll 4
        for (int j = 0; j < G_N; ++j) {
            float4 gb = sbox[j];
            float4 gm = smeta[j];               // {-ga, ga, lab, 0}
            #pragma unroll
            for (int k = 0; k < APT; ++k) {
                float ltx = fmaxf(ax[k], gb.x);
                float lty = fmaxf(ay[k], gb.y);
                float rbx = fminf(az[k], gb.z);
                float rby = fminf(aw[k], gb.w);
                float iw  = fmaxf(rbx - ltx, 0.0f);
                float ih  = fmaxf(rby - lty, 0.0f);
                float inter = iw * ih;
                float sa = (az[k] - ax[k]) * (aw[k] - ay[k]) + 1e-8f;
                float S  = sa + gm.y;
                // iou_j > iou_best <=> inter_j*S_best > inter_best*S_j
                bool better = inter * bS[k] > bi[k] * S;
                bi[k] = better ? inter : bi[k];
                bS[k] = better ? S     : bS[k];
                bl[k] = better ? gm.z  : bl[k];
            }
        }
        #pragma unroll
        for (int k = 0; k < APT; ++k) {
            bool valid = (base + k * BLK) < A_N;
            bool pos = 3.0f * bi[k] >= bS[k];   // max iou >= 0.5
            bool neg = 3.5f * bi[k] <  bS[k];   // max iou <  0.4
            bool tp  = pos && (bl[k] == 0.0f);  // one_hot(assigned, C=1) hit
            float p = __builtin_amdgcn_fmed3f(pv[k], 1e-7f, 1.0f - 1e-7f);
            float q = 1.0f - p;
            float x = tp ? p : q;
            float w = tp ? C_POS * q * q : C_NEG * p * p;
            float l = w * (-__log2f(x));
            l = ((pos | neg) && valid) ? l : 0.0f;
            loss += l;
            cnt  += (pos && valid) ? 1.0f : 0.0f;
        }
    }

    // block reduction: wave shuffle, then cross-wave via LDS, 2 atomics/block
    #pragma unroll
    for (int off = 32; off > 0; off >>= 1) {
        loss += __shfl_down(loss, off);
        cnt  += __shfl_down(cnt, off);
    }
    __shared__ float s_l[4], s_c[4];
    int wid  = t >> 6;
    int lane = t & 63;
    if (lane == 0) { s_l[wid] = loss; s_c[wid] = cnt; }
    __syncthreads();
    if (t == 0) {
        atomicAdd(&ws[b],       s_l[0] + s_l[1] + s_l[2] + s_l[3]);
        atomicAdd(&ws[B_N + b], s_c[0] + s_c[1] + s_c[2] + s_c[3]);
    }
}

__global__ void rnl_final(const float* __restrict__ ws, float* __restrict__ out) {
    if (threadIdx.x == 0) {
        float s = 0.0f;
        #pragma unroll
        for (int b = 0; b < B_N; ++b) {
            s += ws[b] / fmaxf(ws[B_N + b], 1.0f);
        }
        out[0] = s * (1.0f / (float)B_N);
    }
}

extern "C" void kernel_launch(void* const* d_in, const int* in_sizes, int n_in,
                              void* d_out, int out_size, void* d_ws, size_t ws_size,
                              hipStream_t stream) {
    const float* y_true     = (const float*)d_in[0];
    const float* y_classifs = (const float*)d_in[1];
    // d_in[2] = y_regressions: unused by the loss
    const float* anchors    = (const float*)d_in[3];
    float* ws = (float*)d_ws;

    hipMemsetAsync(ws, 0, 2 * B_N * sizeof(float), stream);  // capturable memset node

    dim3 grid(NBX, B_N);
    rnl_main<<<grid, BLK, 0, stream>>>((const float4*)anchors, y_classifs,
                                       y_true, ws);

    rnl_final<<<1, 64, 0, stream>>>(ws, (float*)d_out);
}